// Round 1
// baseline (98.140 us; speedup 1.0000x reference)
//
#include <hip/hip_runtime.h>

// ReadoutLayerMultidim: B=8, N=128, F=256, HID=256, OUT=1
// Factored algorithm:
//   Q[b,h]   = b1[h] + sum_g relu(hp[b,g]) * W1[g,h],  hp = (mean_n x) @ Wp
//   A[b,i,h] = sum_f relu(x[b,i,f]) * W1[256+f, h]
//   Ct[b,h,j]= sum_f relu(x[b,j,f]) * W1[512+f, h]   (transposed for coalesced j)
//   out[b,i,j] = b2 + sum_h relu(Q[b,h] + A[b,i,h] + Ct[b,h,j]) * W2[h]
//
// ws layout (floats): Q @ 0 (2048), A @ 2048 (262144), Ct @ 264192 (262144)

extern "C" __global__ __launch_bounds__(256)
void k1_gemm_pool(const float* __restrict__ x, const float* __restrict__ Wp,
                  const float* __restrict__ W1, const float* __restrict__ b1,
                  float* __restrict__ ws) {
  __shared__ __align__(16) float smem[64*68 + 64*64];
  const int t = threadIdx.x;
  const int blk = blockIdx.x;
  float* Qw = ws;                  // 8*256
  float* Aw = ws + 2048;           // 1024*256 row-major [r][h]
  float* Cw = ws + 2048 + 262144;  // 8 * [256][128] h-major

  if (blk < 128) {
    // ---- GEMM: relu(X)[1024,256] @ W1[256:768].rows -> [1024, 512] ----
    float* As = smem;            // [64][68]  k-major (transposed), padded
    float* Bs = smem + 64 * 68;  // [64][64]
    const int bm = blk & 15;       // row tile (64 rows)
    const int bn = blk >> 4;       // col tile (64 cols of 512)
    const int rbase = (bn < 4) ? 256 : 512;  // W1 row base
    const int cbase = (bn & 3) * 64;         // W1 col base
    const int tx = t & 15, ty = t >> 4;

    float acc[4][4];
#pragma unroll
    for (int p = 0; p < 4; ++p)
#pragma unroll
      for (int q = 0; q < 4; ++q) acc[p][q] = 0.f;

    for (int ks = 0; ks < 256; ks += 64) {
      // stage A-tile: relu(x), transposed into As[kk][m]
#pragma unroll
      for (int s = 0; s < 4; ++s) {
        const int e = t + 256 * s;       // float4-unit index in [0,1024)
        const int m = e >> 4;            // row in tile
        const int kk4 = (e & 15) << 2;   // k offset
        const float4 v = *reinterpret_cast<const float4*>(
            x + (bm * 64 + m) * 256 + ks + kk4);
        As[(kk4 + 0) * 68 + m] = fmaxf(v.x, 0.f);
        As[(kk4 + 1) * 68 + m] = fmaxf(v.y, 0.f);
        As[(kk4 + 2) * 68 + m] = fmaxf(v.z, 0.f);
        As[(kk4 + 3) * 68 + m] = fmaxf(v.w, 0.f);
      }
      // stage B-tile: W1 rows rbase+ks..+63, cols cbase..cbase+63
#pragma unroll
      for (int s = 0; s < 4; ++s) {
        const int e = t + 256 * s;
        const int kk = e >> 4;
        const int n4 = (e & 15) << 2;
        *reinterpret_cast<float4*>(Bs + kk * 64 + n4) =
            *reinterpret_cast<const float4*>(
                W1 + (rbase + ks + kk) * 256 + cbase + n4);
      }
      __syncthreads();
#pragma unroll
      for (int kk = 0; kk < 64; ++kk) {
        const float4 a  = *reinterpret_cast<const float4*>(As + kk * 68 + ty * 4);
        const float4 bv = *reinterpret_cast<const float4*>(Bs + kk * 64 + tx * 4);
        const float av[4]  = {a.x, a.y, a.z, a.w};
        const float bvv[4] = {bv.x, bv.y, bv.z, bv.w};
#pragma unroll
        for (int p = 0; p < 4; ++p)
#pragma unroll
          for (int q = 0; q < 4; ++q)
            acc[p][q] = fmaf(av[p], bvv[q], acc[p][q]);
      }
      __syncthreads();
    }
    // epilogue: cols <256 -> A (row-major), cols >=256 -> Ct (h-major)
#pragma unroll
    for (int p = 0; p < 4; ++p) {
      const int r = bm * 64 + ty * 4 + p;
#pragma unroll
      for (int q = 0; q < 4; ++q) {
        const int C = bn * 64 + tx * 4 + q;
        if (C < 256) {
          Aw[r * 256 + C] = acc[p][q];
        } else {
          const int h = C - 256;
          const int bb = r >> 7, j = r & 127;
          Cw[bb * 32768 + h * 128 + j] = acc[p][q];
        }
      }
    }
  } else {
    // ---- pooled path: one block per batch ----
    const int b = blk - 128;
    float* ml = smem;        // 256: mean vec
    float* rl = smem + 256;  // 256: relu(hp)
    {
      float sum = 0.f;
      const float* xb = x + b * 128 * 256 + t;
      for (int n = 0; n < 128; ++n) sum += xb[n * 256];
      ml[t] = sum * (1.0f / 128.0f);
    }
    __syncthreads();
    {
      float hp = 0.f;
      for (int f = 0; f < 256; ++f) hp = fmaf(ml[f], Wp[f * 256 + t], hp);
      rl[t] = fmaxf(hp, 0.f);
    }
    __syncthreads();
    {
      float q = b1[t];
      for (int g = 0; g < 256; ++g) q = fmaf(rl[g], W1[g * 256 + t], q);
      Qw[b * 256 + t] = q;
    }
  }
}

extern "C" __global__ __launch_bounds__(128)
void k2_final(const float* __restrict__ ws, const float* __restrict__ W2,
              const float* __restrict__ b2, float* __restrict__ out) {
  __shared__ float qa[4 * 256];
  __shared__ float w2l[256];
  const int t = threadIdx.x;            // j
  const int b = blockIdx.x >> 5;        // batch
  const int it = (blockIdx.x & 31) << 2;  // i tile of 4
  const float* Qw = ws;
  const float* Aw = ws + 2048;
  const float* Cw = ws + 2048 + 262144;

#pragma unroll
  for (int s = 0; s < 8; ++s) {
    const int e = t + 128 * s;   // [0,1024)
    const int il = e >> 8;       // i within tile
    const int h = e & 255;
    qa[e] = Qw[b * 256 + h] + Aw[(b * 128 + it + il) * 256 + h];
  }
  w2l[t] = W2[t];
  w2l[t + 128] = W2[t + 128];
  __syncthreads();

  float a0 = 0.f, a1 = 0.f, a2 = 0.f, a3 = 0.f;
  const float* ct = Cw + b * 32768 + t;
#pragma unroll 8
  for (int h = 0; h < 256; ++h) {
    const float c = ct[h * 128];
    const float w = w2l[h];
    a0 = fmaf(fmaxf(qa[h] + c, 0.f), w, a0);
    a1 = fmaf(fmaxf(qa[256 + h] + c, 0.f), w, a1);
    a2 = fmaf(fmaxf(qa[512 + h] + c, 0.f), w, a2);
    a3 = fmaf(fmaxf(qa[768 + h] + c, 0.f), w, a3);
  }
  const float bb = b2[0];
  const int base = (b * 128 + it) * 128 + t;
  out[base +   0] = a0 + bb;
  out[base + 128] = a1 + bb;
  out[base + 256] = a2 + bb;
  out[base + 384] = a3 + bb;
}

extern "C" void kernel_launch(void* const* d_in, const int* in_sizes, int n_in,
                              void* d_out, int out_size, void* d_ws, size_t ws_size,
                              hipStream_t stream) {
  const float* x  = (const float*)d_in[0];
  // d_in[1] = mask: unused by the reference computation (all-ones, never applied)
  const float* Wp = (const float*)d_in[2];
  const float* W1 = (const float*)d_in[3];
  const float* b1 = (const float*)d_in[4];
  const float* W2 = (const float*)d_in[5];
  const float* b2 = (const float*)d_in[6];
  float* ws  = (float*)d_ws;
  float* out = (float*)d_out;

  hipLaunchKernelGGL(k1_gemm_pool, dim3(136), dim3(256), 0, stream,
                     x, Wp, W1, b1, ws);
  hipLaunchKernelGGL(k2_final, dim3(256), dim3(128), 0, stream,
                     ws, W2, b2, out);
}

// Round 2
// 92.529 us; speedup vs baseline: 1.0606x; 1.0606x over previous
//
#include <hip/hip_runtime.h>

// ReadoutLayerMultidim: B=8, N=128, F=256, HID=256, OUT=1
// Factored algorithm:
//   Q[b,h]   = b1[h] + sum_g relu(hp[b,g]) * W1[g,h],  hp = (mean_n x) @ Wp
//   A[b,i,h] = sum_f relu(x[b,i,f]) * W1[256+f, h]
//   Ct[b,h,j]= sum_f relu(x[b,j,f]) * W1[512+f, h]   (transposed for coalesced j)
//   out[b,i,j] = b2 + sum_h relu(Q[b,h] + A[b,i,h] + Ct[b,h,j]) * W2[h]
//
// ws layout (floats): Q @ 0 (2048), A @ 2048 (262144), Ct @ 264192 (262144)

extern "C" __global__ __launch_bounds__(256)
void k1_gemm_pool(const float* __restrict__ x, const float* __restrict__ Wp,
                  const float* __restrict__ W1, const float* __restrict__ b1,
                  float* __restrict__ ws) {
  __shared__ __align__(16) float smem[64 * 34 + 64 * 64];
  const int t = threadIdx.x;
  const int blk = blockIdx.x;
  float* Qw = ws;                  // 8*256
  float* Aw = ws + 2048;           // 1024*256 row-major [r][h]
  float* Cw = ws + 2048 + 262144;  // 8 * [256][128] h-major

  if (blk < 256) {
    // ---- GEMM: relu(X)[1024,256] @ W1-rows -> [1024, 512 virtual] ----
    // 32x64 tile, 256 threads, 2x4 micro-tile. grid: 32 row-tiles x 8 col-tiles.
    float* As = smem;            // [64][34] k-major (transposed), padded
    float* Bs = smem + 64 * 34;  // [64][64]
    const int bm = blk & 31;     // row tile (32 rows)
    const int bn = blk >> 5;     // col tile (64 cols of 512)
    const int rbase = (bn < 4) ? 256 : 512;  // W1 row base
    const int cbase = (bn & 3) * 64;         // W1 col base
    const int tx = t & 15, ty = t >> 4;      // tx: 4 cols, ty: 2 rows

    float acc[2][4];
#pragma unroll
    for (int p = 0; p < 2; ++p)
#pragma unroll
      for (int q = 0; q < 4; ++q) acc[p][q] = 0.f;

    for (int ks = 0; ks < 256; ks += 64) {
      // stage A-tile: relu(x) transposed into As[kk][m]; 2048 floats, 2 float4/thr
#pragma unroll
      for (int s = 0; s < 2; ++s) {
        const int e = t + 256 * s;
        const int m = e >> 4;            // row in tile [0,32)
        const int kk4 = (e & 15) << 2;   // k offset
        const float4 v = *reinterpret_cast<const float4*>(
            x + (bm * 32 + m) * 256 + ks + kk4);
        As[(kk4 + 0) * 34 + m] = fmaxf(v.x, 0.f);
        As[(kk4 + 1) * 34 + m] = fmaxf(v.y, 0.f);
        As[(kk4 + 2) * 34 + m] = fmaxf(v.z, 0.f);
        As[(kk4 + 3) * 34 + m] = fmaxf(v.w, 0.f);
      }
      // stage B-tile: 64k x 64n; 4096 floats, 4 float4/thread
#pragma unroll
      for (int s = 0; s < 4; ++s) {
        const int e = t + 256 * s;
        const int kk = e >> 4;
        const int n4 = (e & 15) << 2;
        *reinterpret_cast<float4*>(Bs + kk * 64 + n4) =
            *reinterpret_cast<const float4*>(
                W1 + (rbase + ks + kk) * 256 + cbase + n4);
      }
      __syncthreads();
#pragma unroll
      for (int kk = 0; kk < 64; ++kk) {
        const float2 a  = *reinterpret_cast<const float2*>(As + kk * 34 + ty * 2);
        const float4 bv = *reinterpret_cast<const float4*>(Bs + kk * 64 + tx * 4);
        const float av[2]  = {a.x, a.y};
        const float bvv[4] = {bv.x, bv.y, bv.z, bv.w};
#pragma unroll
        for (int p = 0; p < 2; ++p)
#pragma unroll
          for (int q = 0; q < 4; ++q)
            acc[p][q] = fmaf(av[p], bvv[q], acc[p][q]);
      }
      __syncthreads();
    }
    // epilogue: cols <256 -> A (row-major), cols >=256 -> Ct (h-major)
#pragma unroll
    for (int p = 0; p < 2; ++p) {
      const int r = bm * 32 + ty * 2 + p;
#pragma unroll
      for (int q = 0; q < 4; ++q) {
        const int C = bn * 64 + tx * 4 + q;
        if (C < 256) {
          Aw[r * 256 + C] = acc[p][q];
        } else {
          const int h = C - 256;
          Cw[(r >> 7) * 32768 + h * 128 + (r & 127)] = acc[p][q];
        }
      }
    }
  } else {
    // ---- pooled path: one block per batch ----
    const int b = blk - 256;
    float* ml = smem;        // 256: mean vec
    float* rl = smem + 256;  // 256: relu(hp)
    {
      float sum = 0.f;
      const float* xb = x + b * 128 * 256 + t;
      for (int n = 0; n < 128; ++n) sum += xb[n * 256];
      ml[t] = sum * (1.0f / 128.0f);
    }
    __syncthreads();
    {
      float hp = 0.f;
      for (int f = 0; f < 256; ++f) hp = fmaf(ml[f], Wp[f * 256 + t], hp);
      rl[t] = fmaxf(hp, 0.f);
    }
    __syncthreads();
    {
      float q = b1[t];
      for (int g = 0; g < 256; ++g) q = fmaf(rl[g], W1[g * 256 + t], q);
      Qw[b * 256 + t] = q;
    }
  }
}

extern "C" __global__ __launch_bounds__(512)
void k2_final(const float* __restrict__ ws, const float* __restrict__ W2,
              const float* __restrict__ b2, float* __restrict__ out) {
  __shared__ float qa[4 * 256];
  __shared__ float w2l[256];
  const int t = threadIdx.x;              // 512 threads: (ti=4) x (j=128)
  const int b = blockIdx.x >> 5;          // batch
  const int it = (blockIdx.x & 31) << 2;  // i tile of 4
  const float* Qw = ws;
  const float* Aw = ws + 2048;
  const float* Cw = ws + 2048 + 262144;

#pragma unroll
  for (int s = 0; s < 2; ++s) {
    const int e = t + 512 * s;   // [0,1024)
    const int il = e >> 8;       // i within tile
    const int h = e & 255;
    qa[e] = Qw[b * 256 + h] + Aw[(b * 128 + it + il) * 256 + h];
  }
  if (t < 256) w2l[t] = W2[t];
  __syncthreads();

  const int j = t & 127;
  const int ti = t >> 7;               // wave-uniform
  const float* ct = Cw + b * 32768 + j;
  const float* qrow = qa + ti * 256;

  float a0 = 0.f, a1 = 0.f;            // split chain: even/odd h
#pragma unroll 8
  for (int h = 0; h < 256; h += 2) {
    a0 = fmaf(fmaxf(qrow[h] + ct[h * 128], 0.f), w2l[h], a0);
    a1 = fmaf(fmaxf(qrow[h + 1] + ct[(h + 1) * 128], 0.f), w2l[h + 1], a1);
  }
  out[(b * 128 + it + ti) * 128 + j] = a0 + a1 + b2[0];
}

extern "C" void kernel_launch(void* const* d_in, const int* in_sizes, int n_in,
                              void* d_out, int out_size, void* d_ws, size_t ws_size,
                              hipStream_t stream) {
  const float* x  = (const float*)d_in[0];
  // d_in[1] = mask: unused by the reference computation (all-ones, never applied)
  const float* Wp = (const float*)d_in[2];
  const float* W1 = (const float*)d_in[3];
  const float* b1 = (const float*)d_in[4];
  const float* W2 = (const float*)d_in[5];
  const float* b2 = (const float*)d_in[6];
  float* ws  = (float*)d_ws;
  float* out = (float*)d_out;

  hipLaunchKernelGGL(k1_gemm_pool, dim3(264), dim3(256), 0, stream,
                     x, Wp, W1, b1, ws);
  hipLaunchKernelGGL(k2_final, dim3(256), dim3(512), 0, stream,
                     ws, W2, b2, out);
}